// Round 2
// baseline (10371.778 us; speedup 1.0000x reference)
//
#include <hip/hip_runtime.h>
#include <hip/hip_bf16.h>

// ---------------------------------------------------------------------------
// 2-layer LSTM (B=256,S=512,E=128,H=256) + LayerNorm + projection.
// Round 2: fix round-1 abort (ws overflow). Chunked over S so scratch fits
// any ws_size >= ~6 MB; T chosen at launch from ws_size (deterministic).
// Numerically identical to the unchunked design (fp32 state carried in ws).
//
// ws layout (bytes), T in {512,...,4}:
//   [0)                xp_c  bf16 [T][B][4H]   T*524288
//   [T*524288)         iobuf bf16 [T][B][<=H]  T*131072  (e chunk / h1 chunk)
//   [T*655360)         wih0b bf16 [1024][128]  262144
//   +262144            whh0b bf16 [1024][256]  524288
//   +524288            wih1b bf16 [1024][256]  524288
//   +524288            whh1b bf16 [1024][256]  524288
//   +524288            bc0   f32  [1024]       4096
//   +4096              bc1   f32  [1024]       4096
//   +4096              h0s,c0s,h1s,c1s f32 [B][H] 4*262144
//   total = T*655360 + 2,891,776
// ---------------------------------------------------------------------------

typedef unsigned short u16;
typedef unsigned int   u32;
using short8 = __attribute__((ext_vector_type(8))) short;
using f32x4  = __attribute__((ext_vector_type(4))) float;

#define NB 256
#define NS 512
#define NE 128
#define NH 256
#define NG 1024  // 4*H

__device__ __forceinline__ u16 f2b(float x) {
  __hip_bfloat16 h = __float2bfloat16(x);
  return __builtin_bit_cast(u16, h);
}
__device__ __forceinline__ float b2f(u16 u) {
  return __builtin_bit_cast(float, (u32)u << 16);
}
__device__ __forceinline__ float sigf(float x) { return 1.0f / (1.0f + __expf(-x)); }
__device__ __forceinline__ float tanhfast(float x) {
  float e = __expf(2.0f * x);
  return 1.0f - 2.0f / (e + 1.0f);
}

// ---------------- prep: fp32 weights -> bf16, combined biases -------------
__global__ __launch_bounds__(256) void prep_weights(
    const float* Wih0, const float* Whh0, const float* bih0, const float* bhh0,
    const float* Wih1, const float* Whh1, const float* bih1, const float* bhh1,
    u16* wih0b, u16* whh0b, u16* wih1b, u16* whh1b, float* bc0, float* bc1) {
  int stride = gridDim.x * blockDim.x;
  int tid = blockIdx.x * blockDim.x + threadIdx.x;
  for (int i = tid; i < NG * NE; i += stride) wih0b[i] = f2b(Wih0[i]);
  for (int i = tid; i < NG * NH; i += stride) {
    whh0b[i] = f2b(Whh0[i]);
    wih1b[i] = f2b(Wih1[i]);
    whh1b[i] = f2b(Whh1[i]);
  }
  for (int i = tid; i < NG; i += stride) {
    bc0[i] = bih0[i] + bhh0[i];
    bc1[i] = bih1[i] + bhh1[i];
  }
}

// ---------------- embedding gather for steps [t0, t0+T) -------------------
// ebuf[(sl*B + b)*NE + d], sl = s - t0. grid = T*32 blocks x 256 thr.
__global__ __launch_bounds__(256) void embed_chunk(const int* __restrict__ x,
                                                   const float* __restrict__ emb,
                                                   u16* __restrict__ ebuf, int t0) {
  int gid = blockIdx.x * 256 + threadIdx.x;
  int d4 = gid & 31;                            // 32 chunks of 4 along E
  int sb = gid >> 5;                            // sl*B + b
  int b  = sb & (NB - 1);
  int sl = sb >> 8;
  int tok = x[b * NS + (t0 + sl)];              // x is [B][S]
  float4 v = make_float4(0.f, 0.f, 0.f, 0.f);
  if (tok != 0) v = *(const float4*)(emb + (size_t)tok * NE + d4 * 4);
  ushort4 o;
  o.x = f2b(v.x); o.y = f2b(v.y); o.z = f2b(v.z); o.w = f2b(v.w);
  *(ushort4*)(ebuf + (size_t)sb * NE + d4 * 4) = o;
}

// ---------------- xp GEMM: C[row][g] = bias[g] + sum_k A[row][k] W[g][k] ---
// A: [T*256][K] bf16 row-major, W: [1024][K] bf16, C: [T*256][1024] bf16.
// grid = (T*2 mblks) x 8 nblks; block 256 (4 waves -> 2x2 quadrants of 64x64)
template <int K>
__global__ __launch_bounds__(256) void xp_gemm(const u16* __restrict__ A,
                                               const u16* __restrict__ W,
                                               const float* __restrict__ bias,
                                               u16* __restrict__ Cout) {
  __shared__ __align__(16) char lds[2 * 128 * 80];  // 80B rows: bank-safe
  char* Asm = lds;
  char* Bsm = lds + 128 * 80;
  int tid = threadIdx.x;
  int w = tid >> 6, l = tid & 63;
  int hi = l >> 4, lo = l & 15;
  int mblk = blockIdx.x >> 3, nblk = blockIdx.x & 7;
  size_t arow0 = (size_t)mblk * 128;
  int g0 = nblk * 128;
  int wm = (w >> 1) * 64, wn = (w & 1) * 64;
  f32x4 acc[4][4] = {};
  int r = tid >> 1, cp = tid & 1;               // staging: thread -> (row, 32B half)

  for (int k0 = 0; k0 < K; k0 += 32) {
    int4 a0 = *(const int4*)(A + (arow0 + r) * K + k0 + cp * 16);
    int4 a1 = *(const int4*)(A + (arow0 + r) * K + k0 + cp * 16 + 8);
    int4 b0 = *(const int4*)(W + (size_t)(g0 + r) * K + k0 + cp * 16);
    int4 b1 = *(const int4*)(W + (size_t)(g0 + r) * K + k0 + cp * 16 + 8);
    *(int4*)(Asm + r * 80 + cp * 32)      = a0;
    *(int4*)(Asm + r * 80 + cp * 32 + 16) = a1;
    *(int4*)(Bsm + r * 80 + cp * 32)      = b0;
    *(int4*)(Bsm + r * 80 + cp * 32 + 16) = b1;
    __syncthreads();
    short8 af[4], bfr[4];
#pragma unroll
    for (int mt = 0; mt < 4; ++mt)
      af[mt] = *(const short8*)(Asm + (wm + mt * 16 + lo) * 80 + hi * 16);
#pragma unroll
    for (int nt = 0; nt < 4; ++nt)
      bfr[nt] = *(const short8*)(Bsm + (wn + nt * 16 + lo) * 80 + hi * 16);
#pragma unroll
    for (int mt = 0; mt < 4; ++mt)
#pragma unroll
      for (int nt = 0; nt < 4; ++nt)
        acc[mt][nt] = __builtin_amdgcn_mfma_f32_16x16x32_bf16(af[mt], bfr[nt], acc[mt][nt], 0, 0, 0);
    __syncthreads();
  }
  // epilogue: D lane mapping col = lane&15, row = (lane>>4)*4 + reg
#pragma unroll
  for (int nt = 0; nt < 4; ++nt) {
    int gc = g0 + wn + nt * 16 + lo;
    float bv = bias[gc];
#pragma unroll
    for (int mt = 0; mt < 4; ++mt) {
      size_t row = arow0 + wm + mt * 16 + hi * 4;
#pragma unroll
      for (int rr = 0; rr < 4; ++rr)
        Cout[(row + rr) * NG + gc] = f2b(acc[mt][nt][rr] + bv);
    }
  }
}

// ---------------- LSTM scan: one layer, T steps of a chunk -----------------
// 16 WGs (batch groups of 16) x 512 thr (8 waves). Per step:
//   gates(1024 x 16) = Whh(1024x256) @ h^T(256x16) + xp_t   via 16x16x32 MFMA
// wave w owns M-tiles {w, w+8, ..., w+56}; lane (hi,lo) holds gate rows
// g = 16*T + hi*4 + r for batch col bg+lo -> cell update fully in registers.
// h kept in LDS [b][k] bf16, XOR swizzle ((b&7)<<4) on byte addr
// (ds_read_b128 B-fragments land 2-way/bank = free). Whh streamed from L2.
// h,c persist across chunks in fp32 state buffers (first chunk zero-inits).
__global__ __launch_bounds__(512) void lstm_scan(const u16* __restrict__ xp,
                                                 const u16* __restrict__ whh,
                                                 u16* __restrict__ h_out,
                                                 float* __restrict__ h_state,
                                                 float* __restrict__ c_state,
                                                 int T, int first) {
  __shared__ __align__(16) u16 h_lds[16 * NH];
  int tid = threadIdx.x;
  int w = tid >> 6, l = tid & 63;
  int hi = l >> 4, lo = l & 15;
  int bg = blockIdx.x * 16;

  float c[2][4];
  if (first) {
    for (int i = tid; i < 16 * NH / 2; i += 512) ((u32*)h_lds)[i] = 0;
#pragma unroll
    for (int grp = 0; grp < 2; ++grp)
#pragma unroll
      for (int r = 0; r < 4; ++r) c[grp][r] = 0.0f;
  } else {
    for (int i = tid; i < 16 * NH; i += 512) {
      int b = i >> 8, k = i & 255;
      u16 hb = f2b(h_state[(size_t)(bg + b) * NH + k]);
      *(u16*)((char*)h_lds + ((b * 512 + k * 2) ^ ((b & 7) << 4))) = hb;
    }
#pragma unroll
    for (int grp = 0; grp < 2; ++grp)
#pragma unroll
      for (int r = 0; r < 4; ++r) {
        int j = 16 * w + 128 * grp + hi * 4 + r;
        c[grp][r] = c_state[(size_t)(bg + lo) * NH + j];
      }
  }
  __syncthreads();

  f32x4 acc[8];
  for (int t = 0; t < T; ++t) {
    // init accumulators from xp (bias already folded in)
    const u16* xpt = xp + ((size_t)t * NB + bg + lo) * NG;
#pragma unroll
    for (int mt = 0; mt < 8; ++mt) {
      int gg = 16 * (w + 8 * mt) + hi * 4;
      ushort4 xv = *(const ushort4*)(xpt + gg);
      f32x4 a;
      a[0] = b2f(xv.x); a[1] = b2f(xv.y); a[2] = b2f(xv.z); a[3] = b2f(xv.w);
      acc[mt] = a;
    }
    // GEMV: 8 k-tiles x 8 m-tiles
#pragma unroll
    for (int kt = 0; kt < 8; ++kt) {
      int kb = kt * 32 + hi * 8;
      short8 bfrag = *(const short8*)((const char*)h_lds +
                      ((lo * 512 + kb * 2) ^ ((lo & 7) << 4)));
#pragma unroll
      for (int mt = 0; mt < 8; ++mt) {
        int grow = 16 * (w + 8 * mt) + lo;
        short8 afrag = *(const short8*)(whh + (size_t)grow * NH + kb);
        acc[mt] = __builtin_amdgcn_mfma_f32_16x16x32_bf16(afrag, bfrag, acc[mt], 0, 0, 0);
      }
    }
    __syncthreads();  // all h_lds reads complete before overwrite
    // elementwise: lane owns gate rows j for batch col (bg+lo)
#pragma unroll
    for (int grp = 0; grp < 2; ++grp) {
#pragma unroll
      for (int r = 0; r < 4; ++r) {
        float iv = sigf(acc[grp][r]);
        float fv = sigf(acc[2 + grp][r]);
        float gv = tanhfast(acc[4 + grp][r]);
        float ov = sigf(acc[6 + grp][r]);
        float cc = fv * c[grp][r] + iv * gv;
        c[grp][r] = cc;
        float hv = ov * tanhfast(cc);
        int j = 16 * w + 128 * grp + hi * 4 + r;
        u16 hb = f2b(hv);
        *(u16*)((char*)h_lds + ((lo * 512 + j * 2) ^ ((lo & 7) << 4))) = hb;
        if (h_out) h_out[((size_t)t * NB + bg + lo) * NH + j] = hb;
        if (t == T - 1) {
          h_state[(size_t)(bg + lo) * NH + j] = hv;
          c_state[(size_t)(bg + lo) * NH + j] = cc;
        }
      }
    }
    __syncthreads();  // h_t visible before next step's GEMV
  }
}

// ---------------- LayerNorm + projection -----------------------------------
__global__ __launch_bounds__(256) void ln_proj(const float* __restrict__ hn,
                                               const float* __restrict__ lng,
                                               const float* __restrict__ lnb,
                                               const float* __restrict__ pW,
                                               const float* __restrict__ pb,
                                               float* __restrict__ out) {
  __shared__ __align__(16) float nbuf[NH];
  __shared__ float red[8];
  int b = blockIdx.x, tid = threadIdx.x;
  float v = hn[(size_t)b * NH + tid];
  float s = v, s2 = v * v;
#pragma unroll
  for (int o = 32; o > 0; o >>= 1) {
    s  += __shfl_down(s, o);
    s2 += __shfl_down(s2, o);
  }
  if ((tid & 63) == 0) { red[tid >> 6] = s; red[4 + (tid >> 6)] = s2; }
  __syncthreads();
  if (tid == 0) {
    red[0] = red[0] + red[1] + red[2] + red[3];
    red[4] = red[4] + red[5] + red[6] + red[7];
  }
  __syncthreads();
  float mean = red[0] * (1.0f / NH);
  float var  = red[4] * (1.0f / NH) - mean * mean;
  float rs = rsqrtf(var + 1e-5f);
  nbuf[tid] = (v - mean) * rs * lng[tid] + lnb[tid];
  __syncthreads();
  if (tid < NE) {
    float a = pb[tid];
    const float* wr = pW + (size_t)tid * NH;
#pragma unroll 4
    for (int j = 0; j < NH; ++j) a = fmaf(nbuf[j], wr[j], a);
    out[(size_t)b * NE + tid] = a;
  }
}

// ---------------------------------------------------------------------------
extern "C" void kernel_launch(void* const* d_in, const int* in_sizes, int n_in,
                              void* d_out, int out_size, void* d_ws, size_t ws_size,
                              hipStream_t stream) {
  const int*   x     = (const int*)d_in[0];
  const float* emb   = (const float*)d_in[1];
  const float* Wih0  = (const float*)d_in[2];
  const float* Whh0  = (const float*)d_in[3];
  const float* bih0  = (const float*)d_in[4];
  const float* bhh0  = (const float*)d_in[5];
  const float* Wih1  = (const float*)d_in[6];
  const float* Whh1  = (const float*)d_in[7];
  const float* bih1  = (const float*)d_in[8];
  const float* bhh1  = (const float*)d_in[9];
  const float* ln_g  = (const float*)d_in[10];
  const float* ln_b  = (const float*)d_in[11];
  const float* projW = (const float*)d_in[12];
  const float* projb = (const float*)d_in[13];

  // pick largest chunk T (divides 512) whose scratch fits ws_size
  const size_t FIXED = 2891776;  // weights + biases + state
  int T = 512;
  while (T > 4 && FIXED + (size_t)T * 655360 > ws_size) T >>= 1;

  char* ws = (char*)d_ws;
  u16*   xp_c  = (u16*)(ws);
  u16*   iobuf = (u16*)(ws + (size_t)T * 524288);   // e chunk / h1 chunk
  char*  wbase = ws + (size_t)T * 655360;
  u16*   wih0b = (u16*)(wbase);
  u16*   whh0b = (u16*)(wbase + 262144);
  u16*   wih1b = (u16*)(wbase + 786432);
  u16*   whh1b = (u16*)(wbase + 1310720);
  float* bc0   = (float*)(wbase + 1835008);
  float* bc1   = (float*)(wbase + 1839104);
  float* h0s   = (float*)(wbase + 1843200);
  float* c0s   = (float*)(wbase + 2105344);
  float* h1s   = (float*)(wbase + 2367488);
  float* c1s   = (float*)(wbase + 2629632);

  prep_weights<<<256, 256, 0, stream>>>(Wih0, Whh0, bih0, bhh0, Wih1, Whh1, bih1, bhh1,
                                        wih0b, whh0b, wih1b, whh1b, bc0, bc1);
  int nch = NS / T;
  for (int c = 0; c < nch; ++c) {
    int t0 = c * T;
    embed_chunk<<<T * 32, 256, 0, stream>>>(x, emb, iobuf, t0);
    xp_gemm<NE><<<T * 16, 256, 0, stream>>>(iobuf, wih0b, bc0, xp_c);
    lstm_scan<<<16, 512, 0, stream>>>(xp_c, whh0b, iobuf, h0s, c0s, T, c == 0);
    xp_gemm<NH><<<T * 16, 256, 0, stream>>>(iobuf, wih1b, bc1, xp_c);
    lstm_scan<<<16, 512, 0, stream>>>(xp_c, whh1b, nullptr, h1s, c1s, T, c == 0);
  }
  ln_proj<<<NB, 256, 0, stream>>>(h1s, ln_g, ln_b, projW, projb, (float*)d_out);
}

// Round 4
// 4402.241 us; speedup vs baseline: 2.3560x; 2.3560x over previous
//
#include <hip/hip_runtime.h>
#include <hip/hip_bf16.h>

// ---------------------------------------------------------------------------
// 2-layer LSTM (B=256,S=512,E=128,H=256) + LayerNorm + projection.
// Round 4: fix round-3 STORE_H double-XOR bug; replace h LDS layout with
// fragment-major + sigma-swizzle => bfrag ds_read_b128 AND h ds_write_b64
// both provably bank-conflict-free, read address step-invariant.
// Whh persistent: 46 frags/lane VGPR + 18 frags/lane LDS (147KB).
// ws layout unchanged from round 2 (chunked over S, T from ws_size).
// ---------------------------------------------------------------------------

typedef unsigned short u16;
typedef unsigned int   u32;
using short8 = __attribute__((ext_vector_type(8))) short;
using f32x4  = __attribute__((ext_vector_type(4))) float;

#define NB 256
#define NS 512
#define NE 128
#define NH 256
#define NG 1024  // 4*H

// scan LDS: weights 8 waves * 18 frags * 64 lanes * 16B = 147456, then h 8KB
#define WLDS_FRAGS 18
#define HOFF 147456
#define SCAN_LDS (HOFF + 16 * NH * 2)   // 155648

__device__ __forceinline__ u16 f2b(float x) {
  __hip_bfloat16 h = __float2bfloat16(x);
  return __builtin_bit_cast(u16, h);
}
__device__ __forceinline__ float b2f(u16 u) {
  return __builtin_bit_cast(float, (u32)u << 16);
}
__device__ __forceinline__ float sigf(float x) { return 1.0f / (1.0f + __expf(-x)); }
__device__ __forceinline__ float tanhfast(float x) {
  float e = __expf(2.0f * x);
  return 1.0f - 2.0f / (e + 1.0f);
}

// ---------------- prep: fp32 weights -> bf16, combined biases -------------
__global__ __launch_bounds__(256) void prep_weights(
    const float* Wih0, const float* Whh0, const float* bih0, const float* bhh0,
    const float* Wih1, const float* Whh1, const float* bih1, const float* bhh1,
    u16* wih0b, u16* whh0b, u16* wih1b, u16* whh1b, float* bc0, float* bc1) {
  int stride = gridDim.x * blockDim.x;
  int tid = blockIdx.x * blockDim.x + threadIdx.x;
  for (int i = tid; i < NG * NE; i += stride) wih0b[i] = f2b(Wih0[i]);
  for (int i = tid; i < NG * NH; i += stride) {
    whh0b[i] = f2b(Whh0[i]);
    wih1b[i] = f2b(Wih1[i]);
    whh1b[i] = f2b(Whh1[i]);
  }
  for (int i = tid; i < NG; i += stride) {
    bc0[i] = bih0[i] + bhh0[i];
    bc1[i] = bih1[i] + bhh1[i];
  }
}

// ---------------- embedding gather for steps [t0, t0+T) -------------------
__global__ __launch_bounds__(256) void embed_chunk(const int* __restrict__ x,
                                                   const float* __restrict__ emb,
                                                   u16* __restrict__ ebuf, int t0) {
  int gid = blockIdx.x * 256 + threadIdx.x;
  int d4 = gid & 31;
  int sb = gid >> 5;                            // sl*B + b
  int b  = sb & (NB - 1);
  int sl = sb >> 8;
  int tok = x[b * NS + (t0 + sl)];              // x is [B][S]
  float4 v = make_float4(0.f, 0.f, 0.f, 0.f);
  if (tok != 0) v = *(const float4*)(emb + (size_t)tok * NE + d4 * 4);
  ushort4 o;
  o.x = f2b(v.x); o.y = f2b(v.y); o.z = f2b(v.z); o.w = f2b(v.w);
  *(ushort4*)(ebuf + (size_t)sb * NE + d4 * 4) = o;
}

// ---------------- xp GEMM (unchanged, passed round 2) ----------------------
template <int K>
__global__ __launch_bounds__(256) void xp_gemm(const u16* __restrict__ A,
                                               const u16* __restrict__ W,
                                               const float* __restrict__ bias,
                                               u16* __restrict__ Cout) {
  __shared__ __align__(16) char lds[2 * 128 * 80];
  char* Asm = lds;
  char* Bsm = lds + 128 * 80;
  int tid = threadIdx.x;
  int w = tid >> 6, l = tid & 63;
  int hi = l >> 4, lo = l & 15;
  int mblk = blockIdx.x >> 3, nblk = blockIdx.x & 7;
  size_t arow0 = (size_t)mblk * 128;
  int g0 = nblk * 128;
  int wm = (w >> 1) * 64, wn = (w & 1) * 64;
  f32x4 acc[4][4] = {};
  int r = tid >> 1, cp = tid & 1;

  for (int k0 = 0; k0 < K; k0 += 32) {
    int4 a0 = *(const int4*)(A + (arow0 + r) * K + k0 + cp * 16);
    int4 a1 = *(const int4*)(A + (arow0 + r) * K + k0 + cp * 16 + 8);
    int4 b0 = *(const int4*)(W + (size_t)(g0 + r) * K + k0 + cp * 16);
    int4 b1 = *(const int4*)(W + (size_t)(g0 + r) * K + k0 + cp * 16 + 8);
    *(int4*)(Asm + r * 80 + cp * 32)      = a0;
    *(int4*)(Asm + r * 80 + cp * 32 + 16) = a1;
    *(int4*)(Bsm + r * 80 + cp * 32)      = b0;
    *(int4*)(Bsm + r * 80 + cp * 32 + 16) = b1;
    __syncthreads();
    short8 af[4], bfr[4];
#pragma unroll
    for (int mt = 0; mt < 4; ++mt)
      af[mt] = *(const short8*)(Asm + (wm + mt * 16 + lo) * 80 + hi * 16);
#pragma unroll
    for (int nt = 0; nt < 4; ++nt)
      bfr[nt] = *(const short8*)(Bsm + (wn + nt * 16 + lo) * 80 + hi * 16);
#pragma unroll
    for (int mt = 0; mt < 4; ++mt)
#pragma unroll
      for (int nt = 0; nt < 4; ++nt)
        acc[mt][nt] = __builtin_amdgcn_mfma_f32_16x16x32_bf16(af[mt], bfr[nt], acc[mt][nt], 0, 0, 0);
    __syncthreads();
  }
#pragma unroll
  for (int nt = 0; nt < 4; ++nt) {
    int gc = g0 + wn + nt * 16 + lo;
    float bv = bias[gc];
#pragma unroll
    for (int mt = 0; mt < 4; ++mt) {
      size_t row = arow0 + wm + mt * 16 + hi * 4;
#pragma unroll
      for (int rr = 0; rr < 4; ++rr)
        Cout[(row + rr) * NG + gc] = f2b(acc[mt][nt][rr] + bv);
    }
  }
}

// ---------------- LSTM scan: persistent weights, frag-major h --------------
// 16 WGs x 512 thr (8 waves), __launch_bounds__(512,2) -> 256 VGPR cap.
// Wave w owns gate rows 16*(w+8*mt)+lane, mt=0..7 (mt pairs = gate type).
// Whh frags (mt,p): p<2 all mt + p==2 mt<2 in LDS (18 slots), rest in VGPR.
// h LDS layout (frag-major): element (b, k), k=32p+8h'+kap stored at byte
//   HOFF + p*1024 + sig(h'*16+b)*16 + kap*2,   sig(x) = x ^ ((x>>3)&7).
// => bfrag read: lane l reads 16B at HOFF+sig(l)*16+p*1024 (step-invariant,
//    64 lanes tile 1024B: conflict-free). h writes (2x ds_write_b64/lane):
//    each 16-lane group fills one 128B row across all 32 banks: conflict-free.
template <bool STORE_H>
__global__ __launch_bounds__(512, 2) void lstm_scan(const u16* __restrict__ xp,
                                                    const u16* __restrict__ whh,
                                                    u16* __restrict__ h_out,
                                                    float* __restrict__ h_state,
                                                    float* __restrict__ c_state,
                                                    int T, int first) {
  extern __shared__ __align__(16) char smem[];
  int tid = threadIdx.x;
  int w = tid >> 6, l = tid & 63;
  int hi = l >> 4, lo = l & 15;
  int bg = blockIdx.x * 16;

  // ---- load Whh into VGPRs + LDS (once) ----
  int wbase = w * (WLDS_FRAGS * 1024) + l * 16;   // per-lane 16B slots
  short8 wfv[8][5];   // p = 3..7
  short8 wfv2[6];     // p == 2, mt = 2..7
#pragma unroll
  for (int mt = 0; mt < 8; ++mt) {
#pragma unroll
    for (int p = 0; p < 8; ++p) {
      const u16* src = whh + (size_t)(16 * (w + 8 * mt) + lo) * NH + p * 32 + hi * 8;
      short8 v = *(const short8*)src;
      if (p < 2)                 *(short8*)(smem + wbase + (p * 8 + mt) * 1024) = v;
      else if (p == 2 && mt < 2) *(short8*)(smem + wbase + (16 + mt) * 1024) = v;
      else if (p == 2)           wfv2[mt - 2] = v;
      else                       wfv[mt][p - 3] = v;
    }
  }

  // ---- init h (LDS, frag-major) and c (regs) ----
  float c[2][4];
  if (first) {
    for (int i = tid; i < 16 * NH / 2; i += 512) ((u32*)(smem + HOFF))[i] = 0;
#pragma unroll
    for (int g = 0; g < 2; ++g)
#pragma unroll
      for (int r = 0; r < 4; ++r) c[g][r] = 0.0f;
  } else {
    for (int i = tid; i < 16 * NH; i += 512) {
      int b = i >> 8, k = i & 255;
      int p = k >> 5, hp = (k >> 3) & 3, kp = k & 7;
      int xx = hp * 16 + b;
      u16 hb = f2b(h_state[(size_t)(bg + b) * NH + k]);
      *(u16*)(smem + HOFF + p * 1024 + (xx ^ ((xx >> 3) & 7)) * 16 + kp * 2) = hb;
    }
#pragma unroll
    for (int g = 0; g < 2; ++g)
#pragma unroll
      for (int r = 0; r < 4; ++r) {
        int j = 16 * w + 128 * g + hi * 4 + r;
        c[g][r] = c_state[(size_t)(bg + lo) * NH + j];
      }
  }
  __syncthreads();

  // ---- step-invariant addresses ----
  int hrd = HOFF + (l ^ ((l >> 3) & 7)) * 16;       // bfrag read base
  int wr[2];                                         // h write (g=0,1)
#pragma unroll
  for (int g = 0; g < 2; ++g) {
    int xx = (2 * (w & 1) + (hi >> 1)) * 16 + lo;   // h'_j*16 + b
    wr[g] = HOFF + (4 * g + (w >> 1)) * 1024 + (xx ^ ((xx >> 3) & 7)) * 16 + 8 * (hi & 1);
  }
  // STORE_H writeback: thread -> (batch bq, k-chunk kc): logical chunk kc
  int bq = tid >> 5, kc = tid & 31;
  int xw = (kc & 3) * 16 + bq;
  int wb_lds = HOFF + (kc >> 2) * 1024 + (xw ^ ((xw >> 3) & 7)) * 16;
  size_t wb_glob = (size_t)(bg + bq) * NH + kc * 8;
  const u16* xp_lane = xp + (size_t)(bg + lo) * NG + 16 * w + 4 * hi;

  // ---- prefetch xp for t=0 ----
  ushort4 xq[8];
#pragma unroll
  for (int mt = 0; mt < 8; ++mt) xq[mt] = *(const ushort4*)(xp_lane + mt * 128);

  f32x4 acc[8];
  for (int t = 0; t < T; ++t) {
    // acc init from prefetched xp (bias folded in by GEMM)
#pragma unroll
    for (int mt = 0; mt < 8; ++mt) {
      f32x4 a;
      a[0] = b2f(xq[mt].x); a[1] = b2f(xq[mt].y);
      a[2] = b2f(xq[mt].z); a[3] = b2f(xq[mt].w);
      acc[mt] = a;
    }
    // prefetch next step's xp (clamped; last reload discarded)
    {
      int tn = (t + 1 < T) ? (t + 1) : (T - 1);
      const u16* xn = xp_lane + ((size_t)tn << 18);
#pragma unroll
      for (int mt = 0; mt < 8; ++mt) xq[mt] = *(const ushort4*)(xn + mt * 128);
    }
    // GEMV: 8 k-slots x 8 m-tiles; bfrag at immediate offset p*1024
#pragma unroll
    for (int p = 0; p < 8; ++p) {
      short8 bf = *(const short8*)(smem + hrd + p * 1024);
#pragma unroll
      for (int mt = 0; mt < 8; ++mt) {
        short8 af;
        if (p < 2)                 af = *(const short8*)(smem + wbase + (p * 8 + mt) * 1024);
        else if (p == 2 && mt < 2) af = *(const short8*)(smem + wbase + (16 + mt) * 1024);
        else if (p == 2)           af = wfv2[mt - 2];
        else                       af = wfv[mt][p - 3];
        acc[mt] = __builtin_amdgcn_mfma_f32_16x16x32_bf16(af, bf, acc[mt], 0, 0, 0);
      }
    }
    __syncthreads();  // h_lds reads complete before overwrite
    // cell update: lane owns gate rows j = 16w+128g+4hi+r, batch col bg+lo
#pragma unroll
    for (int g = 0; g < 2; ++g) {
      u16 hb4[4];
#pragma unroll
      for (int r = 0; r < 4; ++r) {
        float iv = sigf(acc[g][r]);
        float fv = sigf(acc[2 + g][r]);
        float gv = tanhfast(acc[4 + g][r]);
        float ov = sigf(acc[6 + g][r]);
        float cc = fv * c[g][r] + iv * gv;
        c[g][r] = cc;
        float hv = ov * tanhfast(cc);
        hb4[r] = f2b(hv);
        if (t == T - 1) {
          int j = 16 * w + 128 * g + 4 * hi + r;
          h_state[(size_t)(bg + lo) * NH + j] = hv;
          c_state[(size_t)(bg + lo) * NH + j] = cc;
        }
      }
      ushort4 hw;
      hw.x = hb4[0]; hw.y = hb4[1]; hw.z = hb4[2]; hw.w = hb4[3];
      *(ushort4*)(smem + wr[g]) = hw;   // ds_write_b64, conflict-free
    }
    __syncthreads();  // h_t visible
    if (STORE_H) {
      int4 hv4 = *(const int4*)(smem + wb_lds);          // logical chunk kc
      *(int4*)(h_out + wb_glob + ((size_t)t << 16)) = hv4;  // global chunk kc
    }
  }
}

// ---------------- LayerNorm + projection -----------------------------------
__global__ __launch_bounds__(256) void ln_proj(const float* __restrict__ hn,
                                               const float* __restrict__ lng,
                                               const float* __restrict__ lnb,
                                               const float* __restrict__ pW,
                                               const float* __restrict__ pb,
                                               float* __restrict__ out) {
  __shared__ __align__(16) float nbuf[NH];
  __shared__ float red[8];
  int b = blockIdx.x, tid = threadIdx.x;
  float v = hn[(size_t)b * NH + tid];
  float s = v, s2 = v * v;
#pragma unroll
  for (int o = 32; o > 0; o >>= 1) {
    s  += __shfl_down(s, o);
    s2 += __shfl_down(s2, o);
  }
  if ((tid & 63) == 0) { red[tid >> 6] = s; red[4 + (tid >> 6)] = s2; }
  __syncthreads();
  if (tid == 0) {
    red[0] = red[0] + red[1] + red[2] + red[3];
    red[4] = red[4] + red[5] + red[6] + red[7];
  }
  __syncthreads();
  float mean = red[0] * (1.0f / NH);
  float var  = red[4] * (1.0f / NH) - mean * mean;
  float rs = rsqrtf(var + 1e-5f);
  nbuf[tid] = (v - mean) * rs * lng[tid] + lnb[tid];
  __syncthreads();
  if (tid < NE) {
    float a = pb[tid];
    const float* wr = pW + (size_t)tid * NH;
#pragma unroll 4
    for (int j = 0; j < NH; ++j) a = fmaf(nbuf[j], wr[j], a);
    out[(size_t)b * NE + tid] = a;
  }
}

// ---------------------------------------------------------------------------
extern "C" void kernel_launch(void* const* d_in, const int* in_sizes, int n_in,
                              void* d_out, int out_size, void* d_ws, size_t ws_size,
                              hipStream_t stream) {
  const int*   x     = (const int*)d_in[0];
  const float* emb   = (const float*)d_in[1];
  const float* Wih0  = (const float*)d_in[2];
  const float* Whh0  = (const float*)d_in[3];
  const float* bih0  = (const float*)d_in[4];
  const float* bhh0  = (const float*)d_in[5];
  const float* Wih1  = (const float*)d_in[6];
  const float* Whh1  = (const float*)d_in[7];
  const float* bih1  = (const float*)d_in[8];
  const float* bhh1  = (const float*)d_in[9];
  const float* ln_g  = (const float*)d_in[10];
  const float* ln_b  = (const float*)d_in[11];
  const float* projW = (const float*)d_in[12];
  const float* projb = (const float*)d_in[13];

  // raise dynamic-LDS cap for the scan kernels (idempotent, capture-safe)
  hipFuncSetAttribute((const void*)lstm_scan<true>,
                      hipFuncAttributeMaxDynamicSharedMemorySize, SCAN_LDS);
  hipFuncSetAttribute((const void*)lstm_scan<false>,
                      hipFuncAttributeMaxDynamicSharedMemorySize, SCAN_LDS);

  // pick largest chunk T (divides 512) whose scratch fits ws_size
  const size_t FIXED = 2891776;  // weights + biases + state
  int T = 512;
  while (T > 4 && FIXED + (size_t)T * 655360 > ws_size) T >>= 1;

  char* ws = (char*)d_ws;
  u16*   xp_c  = (u16*)(ws);
  u16*   iobuf = (u16*)(ws + (size_t)T * 524288);   // e chunk / h1 chunk
  char*  wbase = ws + (size_t)T * 655360;
  u16*   wih0b = (u16*)(wbase);
  u16*   whh0b = (u16*)(wbase + 262144);
  u16*   wih1b = (u16*)(wbase + 786432);
  u16*   whh1b = (u16*)(wbase + 1310720);
  float* bc0   = (float*)(wbase + 1835008);
  float* bc1   = (float*)(wbase + 1839104);
  float* h0s   = (float*)(wbase + 1843200);
  float* c0s   = (float*)(wbase + 2105344);
  float* h1s   = (float*)(wbase + 2367488);
  float* c1s   = (float*)(wbase + 2629632);

  prep_weights<<<256, 256, 0, stream>>>(Wih0, Whh0, bih0, bhh0, Wih1, Whh1, bih1, bhh1,
                                        wih0b, whh0b, wih1b, whh1b, bc0, bc1);
  int nch = NS / T;
  for (int c = 0; c < nch; ++c) {
    int t0 = c * T;
    embed_chunk<<<T * 32, 256, 0, stream>>>(x, emb, iobuf, t0);
    xp_gemm<NE><<<T * 16, 256, 0, stream>>>(iobuf, wih0b, bc0, xp_c);
    lstm_scan<true><<<16, 512, SCAN_LDS, stream>>>(xp_c, whh0b, iobuf, h0s, c0s, T, c == 0);
    xp_gemm<NH><<<T * 16, 256, 0, stream>>>(iobuf, wih1b, bc1, xp_c);
    lstm_scan<false><<<16, 512, SCAN_LDS, stream>>>(xp_c, whh1b, nullptr, h1s, c1s, T, c == 0);
  }
  ln_proj<<<NB, 256, 0, stream>>>(h1s, ln_g, ln_b, projW, projb, (float*)d_out);
}

// Round 5
// 4004.758 us; speedup vs baseline: 2.5899x; 1.0993x over previous
//
#include <hip/hip_runtime.h>
#include <hip/hip_bf16.h>

// ---------------------------------------------------------------------------
// 2-layer LSTM (B=256,S=512,E=128,H=256) + LayerNorm + projection.
// Round 5: single-barrier scan step via double-buffered h in LDS.
//   Step t: GEMV reads hbuf[t&1]; cell update writes hbuf[(t+1)&1];
//   ONE __syncthreads per step (was 2). Sigma-swizzle layout identical to
//   round 4 (passed). LDS = 147456 (weights) + 2*8192 (h dbuf) = 160 KiB.
// Whh persistent: 46 frags/lane VGPR + 18 frags/lane LDS.
// ws layout unchanged from round 2 (chunked over S, T from ws_size).
// ---------------------------------------------------------------------------

typedef unsigned short u16;
typedef unsigned int   u32;
using short8 = __attribute__((ext_vector_type(8))) short;
using f32x4  = __attribute__((ext_vector_type(4))) float;

#define NB 256
#define NS 512
#define NE 128
#define NH 256
#define NG 1024  // 4*H

// scan LDS: weights 8 waves * 18 frags * 64 lanes * 16B = 147456, then h dbuf
#define WLDS_FRAGS 18
#define HOFF 147456
#define SCAN_LDS (HOFF + 2 * 16 * NH * 2)   // 163840 = 160 KiB (CU max)

__device__ __forceinline__ u16 f2b(float x) {
  __hip_bfloat16 h = __float2bfloat16(x);
  return __builtin_bit_cast(u16, h);
}
__device__ __forceinline__ float b2f(u16 u) {
  return __builtin_bit_cast(float, (u32)u << 16);
}
__device__ __forceinline__ float sigf(float x) { return 1.0f / (1.0f + __expf(-x)); }
__device__ __forceinline__ float tanhfast(float x) {
  float e = __expf(2.0f * x);
  return 1.0f - 2.0f / (e + 1.0f);
}

// ---------------- prep: fp32 weights -> bf16, combined biases -------------
__global__ __launch_bounds__(256) void prep_weights(
    const float* Wih0, const float* Whh0, const float* bih0, const float* bhh0,
    const float* Wih1, const float* Whh1, const float* bih1, const float* bhh1,
    u16* wih0b, u16* whh0b, u16* wih1b, u16* whh1b, float* bc0, float* bc1) {
  int stride = gridDim.x * blockDim.x;
  int tid = blockIdx.x * blockDim.x + threadIdx.x;
  for (int i = tid; i < NG * NE; i += stride) wih0b[i] = f2b(Wih0[i]);
  for (int i = tid; i < NG * NH; i += stride) {
    whh0b[i] = f2b(Whh0[i]);
    wih1b[i] = f2b(Wih1[i]);
    whh1b[i] = f2b(Whh1[i]);
  }
  for (int i = tid; i < NG; i += stride) {
    bc0[i] = bih0[i] + bhh0[i];
    bc1[i] = bih1[i] + bhh1[i];
  }
}

// ---------------- embedding gather for steps [t0, t0+T) -------------------
__global__ __launch_bounds__(256) void embed_chunk(const int* __restrict__ x,
                                                   const float* __restrict__ emb,
                                                   u16* __restrict__ ebuf, int t0) {
  int gid = blockIdx.x * 256 + threadIdx.x;
  int d4 = gid & 31;
  int sb = gid >> 5;                            // sl*B + b
  int b  = sb & (NB - 1);
  int sl = sb >> 8;
  int tok = x[b * NS + (t0 + sl)];              // x is [B][S]
  float4 v = make_float4(0.f, 0.f, 0.f, 0.f);
  if (tok != 0) v = *(const float4*)(emb + (size_t)tok * NE + d4 * 4);
  ushort4 o;
  o.x = f2b(v.x); o.y = f2b(v.y); o.z = f2b(v.z); o.w = f2b(v.w);
  *(ushort4*)(ebuf + (size_t)sb * NE + d4 * 4) = o;
}

// ---------------- xp GEMM (unchanged, passed rounds 2/4) -------------------
template <int K>
__global__ __launch_bounds__(256) void xp_gemm(const u16* __restrict__ A,
                                               const u16* __restrict__ W,
                                               const float* __restrict__ bias,
                                               u16* __restrict__ Cout) {
  __shared__ __align__(16) char lds[2 * 128 * 80];
  char* Asm = lds;
  char* Bsm = lds + 128 * 80;
  int tid = threadIdx.x;
  int w = tid >> 6, l = tid & 63;
  int hi = l >> 4, lo = l & 15;
  int mblk = blockIdx.x >> 3, nblk = blockIdx.x & 7;
  size_t arow0 = (size_t)mblk * 128;
  int g0 = nblk * 128;
  int wm = (w >> 1) * 64, wn = (w & 1) * 64;
  f32x4 acc[4][4] = {};
  int r = tid >> 1, cp = tid & 1;

  for (int k0 = 0; k0 < K; k0 += 32) {
    int4 a0 = *(const int4*)(A + (arow0 + r) * K + k0 + cp * 16);
    int4 a1 = *(const int4*)(A + (arow0 + r) * K + k0 + cp * 16 + 8);
    int4 b0 = *(const int4*)(W + (size_t)(g0 + r) * K + k0 + cp * 16);
    int4 b1 = *(const int4*)(W + (size_t)(g0 + r) * K + k0 + cp * 16 + 8);
    *(int4*)(Asm + r * 80 + cp * 32)      = a0;
    *(int4*)(Asm + r * 80 + cp * 32 + 16) = a1;
    *(int4*)(Bsm + r * 80 + cp * 32)      = b0;
    *(int4*)(Bsm + r * 80 + cp * 32 + 16) = b1;
    __syncthreads();
    short8 af[4], bfr[4];
#pragma unroll
    for (int mt = 0; mt < 4; ++mt)
      af[mt] = *(const short8*)(Asm + (wm + mt * 16 + lo) * 80 + hi * 16);
#pragma unroll
    for (int nt = 0; nt < 4; ++nt)
      bfr[nt] = *(const short8*)(Bsm + (wn + nt * 16 + lo) * 80 + hi * 16);
#pragma unroll
    for (int mt = 0; mt < 4; ++mt)
#pragma unroll
      for (int nt = 0; nt < 4; ++nt)
        acc[mt][nt] = __builtin_amdgcn_mfma_f32_16x16x32_bf16(af[mt], bfr[nt], acc[mt][nt], 0, 0, 0);
    __syncthreads();
  }
#pragma unroll
  for (int nt = 0; nt < 4; ++nt) {
    int gc = g0 + wn + nt * 16 + lo;
    float bv = bias[gc];
#pragma unroll
    for (int mt = 0; mt < 4; ++mt) {
      size_t row = arow0 + wm + mt * 16 + hi * 4;
#pragma unroll
      for (int rr = 0; rr < 4; ++rr)
        Cout[(row + rr) * NG + gc] = f2b(acc[mt][nt][rr] + bv);
    }
  }
}

// ---------------- LSTM scan: persistent weights, h double-buffer -----------
// 16 WGs x 512 thr (8 waves), __launch_bounds__(512,2) -> 256 VGPR cap.
// Wave w owns gate rows 16*(w+8*mt)+lane, mt=0..7 (mt pairs = gate type).
// Whh frags (mt,p): p<2 all mt + p==2 mt<2 in LDS (18 slots), rest in VGPR.
// h LDS layout (frag-major, per buffer): element (b,k), k=32p+8h'+kap at
//   buf + p*1024 + sig(h'*16+b)*16 + kap*2,  sig(x)=x^((x>>3)&7)
// (bfrag ds_read_b128 and h ds_write_b64 both conflict-free; verified R4).
// Double buffer: step t reads buf[t&1], writes buf[(t+1)&1] => ONE barrier.
template <bool STORE_H>
__global__ __launch_bounds__(512, 2) void lstm_scan(const u16* __restrict__ xp,
                                                    const u16* __restrict__ whh,
                                                    u16* __restrict__ h_out,
                                                    float* __restrict__ h_state,
                                                    float* __restrict__ c_state,
                                                    int T, int first) {
  extern __shared__ __align__(16) char smem[];
  int tid = threadIdx.x;
  int w = tid >> 6, l = tid & 63;
  int hi = l >> 4, lo = l & 15;
  int bg = blockIdx.x * 16;

  // ---- load Whh into VGPRs + LDS (once) ----
  int wbase = w * (WLDS_FRAGS * 1024) + l * 16;   // per-lane 16B slots
  short8 wfv[8][5];   // p = 3..7
  short8 wfv2[6];     // p == 2, mt = 2..7
#pragma unroll
  for (int mt = 0; mt < 8; ++mt) {
#pragma unroll
    for (int p = 0; p < 8; ++p) {
      const u16* src = whh + (size_t)(16 * (w + 8 * mt) + lo) * NH + p * 32 + hi * 8;
      short8 v = *(const short8*)src;
      if (p < 2)                 *(short8*)(smem + wbase + (p * 8 + mt) * 1024) = v;
      else if (p == 2 && mt < 2) *(short8*)(smem + wbase + (16 + mt) * 1024) = v;
      else if (p == 2)           wfv2[mt - 2] = v;
      else                       wfv[mt][p - 3] = v;
    }
  }

  // ---- init h (LDS buffer 0, frag-major) and c (regs) ----
  float c[2][4];
  if (first) {
    for (int i = tid; i < 16 * NH / 2; i += 512) ((u32*)(smem + HOFF))[i] = 0;
#pragma unroll
    for (int g = 0; g < 2; ++g)
#pragma unroll
      for (int r = 0; r < 4; ++r) c[g][r] = 0.0f;
  } else {
    for (int i = tid; i < 16 * NH; i += 512) {
      int b = i >> 8, k = i & 255;
      int p = k >> 5, hp = (k >> 3) & 3, kp = k & 7;
      int xx = hp * 16 + b;
      u16 hb = f2b(h_state[(size_t)(bg + b) * NH + k]);
      *(u16*)(smem + HOFF + p * 1024 + (xx ^ ((xx >> 3) & 7)) * 16 + kp * 2) = hb;
    }
#pragma unroll
    for (int g = 0; g < 2; ++g)
#pragma unroll
      for (int r = 0; r < 4; ++r) {
        int j = 16 * w + 128 * g + hi * 4 + r;
        c[g][r] = c_state[(size_t)(bg + lo) * NH + j];
      }
  }
  __syncthreads();

  // ---- step-invariant offsets (relative to h buffer base) ----
  int rdoff = (l ^ ((l >> 3) & 7)) * 16;            // bfrag read offset
  int wroff[2];                                      // h write offsets (g=0,1)
#pragma unroll
  for (int g = 0; g < 2; ++g) {
    int xx = (2 * (w & 1) + (hi >> 1)) * 16 + lo;   // h'_j*16 + b
    wroff[g] = (4 * g + (w >> 1)) * 1024 + (xx ^ ((xx >> 3) & 7)) * 16 + 8 * (hi & 1);
  }
  // STORE_H writeback: thread -> (batch bq, k-chunk kc): logical chunk kc
  int bq = tid >> 5, kc = tid & 31;
  int xw = (kc & 3) * 16 + bq;
  int wboff = (kc >> 2) * 1024 + (xw ^ ((xw >> 3) & 7)) * 16;
  size_t wb_glob = (size_t)(bg + bq) * NH + kc * 8;
  const u16* xp_lane = xp + (size_t)(bg + lo) * NG + 16 * w + 4 * hi;

  // ---- prefetch xp for t=0 ----
  ushort4 xq[8];
#pragma unroll
  for (int mt = 0; mt < 8; ++mt) xq[mt] = *(const ushort4*)(xp_lane + mt * 128);

  f32x4 acc[8];
  for (int t = 0; t < T; ++t) {
    int rbase = HOFF + ((t & 1) << 13);       // read buffer (h_{t-1})
    int wbbase = HOFF + ((~t & 1) << 13);     // write buffer (h_t)
    // acc init from prefetched xp (bias folded in by GEMM)
#pragma unroll
    for (int mt = 0; mt < 8; ++mt) {
      f32x4 a;
      a[0] = b2f(xq[mt].x); a[1] = b2f(xq[mt].y);
      a[2] = b2f(xq[mt].z); a[3] = b2f(xq[mt].w);
      acc[mt] = a;
    }
    // prefetch next step's xp (clamped; last reload discarded)
    {
      int tn = (t + 1 < T) ? (t + 1) : (T - 1);
      const u16* xn = xp_lane + ((size_t)tn << 18);
#pragma unroll
      for (int mt = 0; mt < 8; ++mt) xq[mt] = *(const ushort4*)(xn + mt * 128);
    }
    // GEMV: 8 k-slots x 8 m-tiles; bfrag at rbase + rdoff + p*1024
#pragma unroll
    for (int p = 0; p < 8; ++p) {
      short8 bf = *(const short8*)(smem + rbase + rdoff + p * 1024);
#pragma unroll
      for (int mt = 0; mt < 8; ++mt) {
        short8 af;
        if (p < 2)                 af = *(const short8*)(smem + wbase + (p * 8 + mt) * 1024);
        else if (p == 2 && mt < 2) af = *(const short8*)(smem + wbase + (16 + mt) * 1024);
        else if (p == 2)           af = wfv2[mt - 2];
        else                       af = wfv[mt][p - 3];
        acc[mt] = __builtin_amdgcn_mfma_f32_16x16x32_bf16(af, bf, acc[mt], 0, 0, 0);
      }
    }
    // cell update: lane owns gate rows j = 16w+128g+4hi+r, batch col bg+lo
    // writes h_t into the OTHER buffer -> no read/write hazard, no barrier here
#pragma unroll
    for (int g = 0; g < 2; ++g) {
      u16 hb4[4];
#pragma unroll
      for (int r = 0; r < 4; ++r) {
        float iv = sigf(acc[g][r]);
        float fv = sigf(acc[2 + g][r]);
        float gv = tanhfast(acc[4 + g][r]);
        float ov = sigf(acc[6 + g][r]);
        float cc = fv * c[g][r] + iv * gv;
        c[g][r] = cc;
        float hv = ov * tanhfast(cc);
        hb4[r] = f2b(hv);
        if (t == T - 1) {
          int j = 16 * w + 128 * g + 4 * hi + r;
          h_state[(size_t)(bg + lo) * NH + j] = hv;
          c_state[(size_t)(bg + lo) * NH + j] = cc;
        }
      }
      ushort4 hw;
      hw.x = hb4[0]; hw.y = hb4[1]; hw.z = hb4[2]; hw.w = hb4[3];
      *(ushort4*)(smem + wbbase + wroff[g]) = hw;   // ds_write_b64, conflict-free
    }
    __syncthreads();  // h_t visible; ONLY barrier in the step
    if (STORE_H) {
      int4 hv4 = *(const int4*)(smem + wbbase + wboff);     // logical chunk kc
      *(int4*)(h_out + wb_glob + ((size_t)t << 16)) = hv4;  // global chunk kc
    }
  }
}

// ---------------- LayerNorm + projection -----------------------------------
__global__ __launch_bounds__(256) void ln_proj(const float* __restrict__ hn,
                                               const float* __restrict__ lng,
                                               const float* __restrict__ lnb,
                                               const float* __restrict__ pW,
                                               const float* __restrict__ pb,
                                               float* __restrict__ out) {
  __shared__ __align__(16) float nbuf[NH];
  __shared__ float red[8];
  int b = blockIdx.x, tid = threadIdx.x;
  float v = hn[(size_t)b * NH + tid];
  float s = v, s2 = v * v;
#pragma unroll
  for (int o = 32; o > 0; o >>= 1) {
    s  += __shfl_down(s, o);
    s2 += __shfl_down(s2, o);
  }
  if ((tid & 63) == 0) { red[tid >> 6] = s; red[4 + (tid >> 6)] = s2; }
  __syncthreads();
  if (tid == 0) {
    red[0] = red[0] + red[1] + red[2] + red[3];
    red[4] = red[4] + red[5] + red[6] + red[7];
  }
  __syncthreads();
  float mean = red[0] * (1.0f / NH);
  float var  = red[4] * (1.0f / NH) - mean * mean;
  float rs = rsqrtf(var + 1e-5f);
  nbuf[tid] = (v - mean) * rs * lng[tid] + lnb[tid];
  __syncthreads();
  if (tid < NE) {
    float a = pb[tid];
    const float* wr = pW + (size_t)tid * NH;
#pragma unroll 4
    for (int j = 0; j < NH; ++j) a = fmaf(nbuf[j], wr[j], a);
    out[(size_t)b * NE + tid] = a;
  }
}

// ---------------------------------------------------------------------------
extern "C" void kernel_launch(void* const* d_in, const int* in_sizes, int n_in,
                              void* d_out, int out_size, void* d_ws, size_t ws_size,
                              hipStream_t stream) {
  const int*   x     = (const int*)d_in[0];
  const float* emb   = (const float*)d_in[1];
  const float* Wih0  = (const float*)d_in[2];
  const float* Whh0  = (const float*)d_in[3];
  const float* bih0  = (const float*)d_in[4];
  const float* bhh0  = (const float*)d_in[5];
  const float* Wih1  = (const float*)d_in[6];
  const float* Whh1  = (const float*)d_in[7];
  const float* bih1  = (const float*)d_in[8];
  const float* bhh1  = (const float*)d_in[9];
  const float* ln_g  = (const float*)d_in[10];
  const float* ln_b  = (const float*)d_in[11];
  const float* projW = (const float*)d_in[12];
  const float* projb = (const float*)d_in[13];

  // raise dynamic-LDS cap for the scan kernels (host-side attr, capture-safe)
  hipFuncSetAttribute((const void*)lstm_scan<true>,
                      hipFuncAttributeMaxDynamicSharedMemorySize, SCAN_LDS);
  hipFuncSetAttribute((const void*)lstm_scan<false>,
                      hipFuncAttributeMaxDynamicSharedMemorySize, SCAN_LDS);

  // pick largest chunk T (divides 512) whose scratch fits ws_size
  const size_t FIXED = 2891776;  // weights + biases + state
  int T = 512;
  while (T > 4 && FIXED + (size_t)T * 655360 > ws_size) T >>= 1;

  char* ws = (char*)d_ws;
  u16*   xp_c  = (u16*)(ws);
  u16*   iobuf = (u16*)(ws + (size_t)T * 524288);   // e chunk / h1 chunk
  char*  wbase = ws + (size_t)T * 655360;
  u16*   wih0b = (u16*)(wbase);
  u16*   whh0b = (u16*)(wbase + 262144);
  u16*   wih1b = (u16*)(wbase + 786432);
  u16*   whh1b = (u16*)(wbase + 1310720);
  float* bc0   = (float*)(wbase + 1835008);
  float* bc1   = (float*)(wbase + 1839104);
  float* h0s   = (float*)(wbase + 1843200);
  float* c0s   = (float*)(wbase + 2105344);
  float* h1s   = (float*)(wbase + 2367488);
  float* c1s   = (float*)(wbase + 2629632);

  prep_weights<<<256, 256, 0, stream>>>(Wih0, Whh0, bih0, bhh0, Wih1, Whh1, bih1, bhh1,
                                        wih0b, whh0b, wih1b, whh1b, bc0, bc1);
  int nch = NS / T;
  for (int c = 0; c < nch; ++c) {
    int t0 = c * T;
    embed_chunk<<<T * 32, 256, 0, stream>>>(x, emb, iobuf, t0);
    xp_gemm<NE><<<T * 16, 256, 0, stream>>>(iobuf, wih0b, bc0, xp_c);
    lstm_scan<true><<<16, 512, SCAN_LDS, stream>>>(xp_c, whh0b, iobuf, h0s, c0s, T, c == 0);
    xp_gemm<NH><<<T * 16, 256, 0, stream>>>(iobuf, wih1b, bc1, xp_c);
    lstm_scan<false><<<16, 512, SCAN_LDS, stream>>>(xp_c, whh1b, nullptr, h1s, c1s, T, c == 0);
  }
  ln_proj<<<NB, 256, 0, stream>>>(h1s, ln_g, ln_b, projW, projb, (float*)d_out);
}